// Round 13
// baseline (167.132 us; speedup 1.0000x reference)
//
#include <hip/hip_runtime.h>

// LocalAutoCorr2D: out[b,iy,ix,c,dy,dx] =
//   sum_{u,v in [0,8)} x[b,c,4iy+u,4ix+v] * x[b,c,4iy+dy+u-4,4ix+dx+v-4]  (zero-padded)
//
// B=4 C=128 H=W=128, kh=kw=8, sh=sw=4, nh=nw=31.
// r13: NO LDS AT ALL. Per-block compute working set (4ch x 27rows x 172B ~ 19KB)
// fits L1 (32KB/CU); rw rows are read directly from global (4x dwordx4/row),
// L1/L2-hit after first touch. Removes: stage phase, __syncthreads, LDS pipe
// contention, all bank conflicts. Thread = (cs, px, py, half), acc[4][8],
// ks rolling register cache as before. Direct register->global stores.
// XCD-chunked swizzle keeps each XCD's x-slice (~4MB) L2-resident.

#define Cn 128
#define Hn 128
#define Wn 128
#define NH 31
#define NW 31
#define CB 4             // channels per block
#define PXT 8            // x positions per block
#define PYT 4            // y positions per block
#define RSPAN 43         // floats per thread-row window span check ((PXT-1)*4+15)

__global__ __launch_bounds__(256)
void lac_kernel(const float* __restrict__ x, float* __restrict__ out) {
    // XCD-chunked swizzle: 4096 blocks, 512 consecutive logical ids per XCD.
    const int bid = blockIdx.x;
    const int lg = ((bid & 7) << 9) | (bid >> 3);
    const int tx = lg & 3;           // x tile 0..3
    const int ty = (lg >> 2) & 7;    // y tile 0..7
    const int ct = (lg >> 5) & 31;   // channel tile 0..31
    const int b  = lg >> 10;         // batch 0..3
    const int c0 = ct * CB;
    const int gy0 = ty * (PYT * 4) - 4;
    const int gx0 = tx * (PXT * 4) - 4;
    const int tid = threadIdx.x;

    // ---- thread mapping: (cs, px, py, half); acc[d][dx], dy = half*4+d ----
    const int cs   = tid & 3;
    const int px   = (tid >> 2) & 7;
    const int py   = (tid >> 5) & 3;
    const int half = tid >> 7;                 // wave-uniform
    const int c     = c0 + cs;
    const int ybase = gy0 + py * 4;            // absolute row of thread-row R=0
    const int xb    = gx0 + px * 4;            // absolute col of rw[0]
    const float* xptr = x + (((ptrdiff_t)(b * Cn + c) * Hn + ybase) * Wn + xb);
    const bool xsafe = (gx0 >= 0) && (gx0 + RSPAN <= Wn);   // block-uniform

    float acc[4][8];
#pragma unroll
    for (int i = 0; i < 4; ++i)
#pragma unroll
        for (int j = 0; j < 8; ++j) acc[i][j] = 0.0f;

    float ks[4][8];   // rolling cache: ks[row&3][v] = X[row][v+4] (cols 4..11)

    // Load thread-row R (absolute y = ybase+R), cols xb..xb+15, zero-padded.
#define LOAD_RW_G(R)                                                            \
    float rw[16];                                                               \
    {                                                                           \
        const int yy = ybase + (R);                                             \
        const float* rp = xptr + (ptrdiff_t)(R) * Wn;                           \
        if ((unsigned)yy < (unsigned)Hn && xsafe) {                             \
            float4 q0 = *reinterpret_cast<const float4*>(rp + 0);               \
            float4 q1 = *reinterpret_cast<const float4*>(rp + 4);               \
            float4 q2 = *reinterpret_cast<const float4*>(rp + 8);               \
            float4 q3 = *reinterpret_cast<const float4*>(rp + 12);              \
            rw[0]=q0.x; rw[1]=q0.y; rw[2]=q0.z; rw[3]=q0.w;                     \
            rw[4]=q1.x; rw[5]=q1.y; rw[6]=q1.z; rw[7]=q1.w;                     \
            rw[8]=q2.x; rw[9]=q2.y; rw[10]=q2.z; rw[11]=q2.w;                   \
            rw[12]=q3.x; rw[13]=q3.y; rw[14]=q3.z; rw[15]=q3.w;                 \
        } else if ((unsigned)yy < (unsigned)Hn) {                               \
            _Pragma("unroll")                                                   \
            for (int e = 0; e < 16; ++e) {                                      \
                const int xe = xb + e;                                          \
                rw[e] = ((unsigned)xe < (unsigned)Wn) ? rp[e] : 0.0f;           \
            }                                                                   \
        } else {                                                                \
            _Pragma("unroll")                                                   \
            for (int e = 0; e < 16; ++e) rw[e] = 0.0f;                          \
        }                                                                       \
    }

    if (half == 0) {
        // dy = d. Descending sweep R=11..0. At row R: shifted = rw (row R),
        // base row cached in ks[(R-d)&3] (saved 4-d iters ago).
#pragma unroll
        for (int ii = 0; ii < 12; ++ii) {
            const int R = 11 - ii;
            LOAD_RW_G(R)
#pragma unroll
            for (int d = 0; d < 4; ++d) {
                if (R >= d && R <= 7 + d) {          // compile-time predicate
#pragma unroll
                    for (int v = 0; v < 8; ++v) {
                        const float bv = ks[(R - d) & 3][v];
#pragma unroll
                        for (int dx = 0; dx < 8; ++dx)
                            acc[d][dx] = fmaf(bv, rw[dx + v], acc[d][dx]);
                    }
                }
            }
#pragma unroll
            for (int v = 0; v < 8; ++v) ks[R & 3][v] = rw[4 + v];
        }
    } else {
        // dy = 4+d. Ascending sweep R=4..14. d=0 -> current rw[4..11],
        // d>=1 -> ks[(R-d)&3] (saved d iters ago).
#pragma unroll
        for (int ii = 0; ii < 11; ++ii) {
            const int R = 4 + ii;
            LOAD_RW_G(R)
#pragma unroll
            for (int d = 0; d < 4; ++d) {
                if (R >= 4 + d && R <= 11 + d) {     // compile-time predicate
#pragma unroll
                    for (int v = 0; v < 8; ++v) {
                        const float bv = (d == 0) ? rw[4 + v] : ks[(R - d) & 3][v];
#pragma unroll
                        for (int dx = 0; dx < 8; ++dx)
                            acc[d][dx] = fmaf(bv, rw[dx + v], acc[d][dx]);
                    }
                }
            }
#pragma unroll
            for (int v = 0; v < 8; ++v) ks[R & 3][v] = rw[4 + v];
        }
    }
#undef LOAD_RW_G

    // ---- direct store: thread's 32 outputs = one contiguous 128B chunk ----
    // out index = ((b,iy,ix)*Cn + c0+cs)*64 + (half*4+d)*8 + dx
    const int iy = ty * PYT + py;
    const int ix = tx * PXT + px;
    if (iy < NH && ix < NW) {
        float* o = out + ((((size_t)b * NH + iy) * NW + ix) * Cn + c) * 64
                       + half * 32;
#pragma unroll
        for (int d = 0; d < 4; ++d) {
            *reinterpret_cast<float4*>(o + d * 8 + 0) =
                make_float4(acc[d][0], acc[d][1], acc[d][2], acc[d][3]);
            *reinterpret_cast<float4*>(o + d * 8 + 4) =
                make_float4(acc[d][4], acc[d][5], acc[d][6], acc[d][7]);
        }
    }
}

extern "C" void kernel_launch(void* const* d_in, const int* in_sizes, int n_in,
                              void* d_out, int out_size, void* d_ws, size_t ws_size,
                              hipStream_t stream) {
    const float* x = (const float*)d_in[0];
    float* out = (float*)d_out;
    // grid = b(4) * ct(32) * ty(8) * tx(4) = 4096 blocks
    lac_kernel<<<dim3(4096), dim3(256), 0, stream>>>(x, out);
}